// Round 1
// baseline (488.527 us; speedup 1.0000x reference)
//
#include <hip/hip_runtime.h>

#define B_ 256
#define T_ 512
#define K_ 128

// One block per batch. 512 threads = 4 groups (h=0..3) x 128 columns (j).
// Thread (h,j) owns transitions rows [32h,32h+32) of column j in registers.
// State (K floats) lives in LDS; backpointers (T-1 x K bytes) live in LDS.
__global__ __launch_bounds__(512) void viterbi_kernel(
    const float* __restrict__ pot,     // B,T,K
    const float* __restrict__ trans,   // K,K
    const int*   __restrict__ lens,    // B
    unsigned char* __restrict__ tags)  // B,T (workspace)
{
  __shared__ __align__(16) float state[K_];
  __shared__ float part_m[4][K_];
  __shared__ int   part_i[4][K_];
  __shared__ unsigned char bp[T_ - 1][K_];   // 65408 bytes

  const int b   = blockIdx.x;
  const int tid = threadIdx.x;
  const int j   = tid & (K_ - 1);
  const int h   = tid >> 7;

  // Load my transitions column chunk into registers (coalesced across j).
  float tr[32];
  {
    const float* tp = trans + (h * 32) * K_ + j;
#pragma unroll
    for (int r = 0; r < 32; ++r) tr[r] = tp[r * K_];
  }

  const int L = lens[b];
  const float* potb = pot + (size_t)b * T_ * K_;

  if (tid < K_) state[tid] = potb[tid];
  __syncthreads();

  for (int t = 1; t < L; ++t) {
    // Prefetch this step's emission early (latency hidden under partial loop).
    float x = 0.0f;
    if (tid < K_) x = potb[t * K_ + j];

    // Partial argmax over i in [32h, 32h+32), 4 independent chains for ILP.
    float m0 = -INFINITY, m1 = -INFINITY, m2 = -INFINITY, m3 = -INFINITY;
    int   i0 = 0, i1 = 1, i2 = 2, i3 = 3;
    const float4* s4 = reinterpret_cast<const float4*>(&state[h * 32]);
#pragma unroll
    for (int r = 0; r < 8; ++r) {
      float4 sv = s4[r];
      float v0 = sv.x + tr[4 * r + 0]; if (v0 > m0) { m0 = v0; i0 = 4 * r + 0; }
      float v1 = sv.y + tr[4 * r + 1]; if (v1 > m1) { m1 = v1; i1 = 4 * r + 1; }
      float v2 = sv.z + tr[4 * r + 2]; if (v2 > m2) { m2 = v2; i2 = 4 * r + 2; }
      float v3 = sv.w + tr[4 * r + 3]; if (v3 > m3) { m3 = v3; i3 = 4 * r + 3; }
    }
    // Combine chains with exact first-occurrence tie-break (indices interleave).
    float m = m0; int ii = i0;
    if (m1 > m || (m1 == m && i1 < ii)) { m = m1; ii = i1; }
    if (m2 > m || (m2 == m && i2 < ii)) { m = m2; ii = i2; }
    if (m3 > m || (m3 == m && i3 < ii)) { m = m3; ii = i3; }
    part_m[h][j] = m;
    part_i[h][j] = ii + h * 32;
    __syncthreads();

    if (tid < K_) {
      float bm = part_m[0][j]; int bi = part_i[0][j];
#pragma unroll
      for (int g = 1; g < 4; ++g) {
        float gm = part_m[g][j]; int gi = part_i[g][j];
        // Higher g holds strictly higher indices: strict > keeps lowest index.
        if (gm > bm) { bm = gm; bi = gi; }
      }
      state[j]      = x + bm;
      bp[t - 1][j]  = (unsigned char)bi;
    }
    __syncthreads();
  }

  // Positions p >= L decode to tag 0 (reference semantics).
  {
    int p = L + tid;
    if (p < T_) tags[(size_t)b * T_ + p] = 0;
  }

  // Final argmax over state[0..127] by wave 0 (first-occurrence ties),
  // then serial backtrace through LDS backpointers by lane 0.
  if (tid < 64) {
    float m = state[tid]; int ix = tid;
    float v = state[tid + 64];
    if (v > m) { m = v; ix = tid + 64; }
#pragma unroll
    for (int d = 1; d < 64; d <<= 1) {
      float mp = __shfl_xor(m, d);
      int   ip = __shfl_xor(ix, d);
      if (mp > m || (mp == m && ip < ix)) { m = mp; ix = ip; }
    }
    if (tid == 0) {
      int tag = ix;
      unsigned char* tb = tags + (size_t)b * T_;
      tb[L - 1] = (unsigned char)tag;
      for (int p = L - 2; p >= 0; --p) {
        tag = bp[p][tag];
        tb[p] = (unsigned char)tag;
      }
    }
  }
}

// out[b][t][k] = (k == tags[b][t]). One float4 per thread.
__global__ __launch_bounds__(256) void onehot_kernel(
    const unsigned char* __restrict__ tags, float* __restrict__ out)
{
  size_t i = (size_t)blockIdx.x * blockDim.x + threadIdx.x;  // float4 index
  int tag = tags[i >> 5];           // 32 float4s per (b,t) row
  int k   = (int)(i & 31) * 4;
  float4 v;
  v.x = (k     == tag) ? 1.0f : 0.0f;
  v.y = (k + 1 == tag) ? 1.0f : 0.0f;
  v.z = (k + 2 == tag) ? 1.0f : 0.0f;
  v.w = (k + 3 == tag) ? 1.0f : 0.0f;
  reinterpret_cast<float4*>(out)[i] = v;
}

extern "C" void kernel_launch(void* const* d_in, const int* in_sizes, int n_in,
                              void* d_out, int out_size, void* d_ws, size_t ws_size,
                              hipStream_t stream) {
  const float* pot   = (const float*)d_in[0];
  const float* trans = (const float*)d_in[1];
  const int*   lens  = (const int*)d_in[2];
  float* out = (float*)d_out;
  unsigned char* tags = (unsigned char*)d_ws;  // B*T bytes

  viterbi_kernel<<<B_, 512, 0, stream>>>(pot, trans, lens, tags);

  const int n4 = (B_ * T_ * K_) / 4;           // 4,194,304 float4 stores
  onehot_kernel<<<n4 / 256, 256, 0, stream>>>(tags, out);
}